// Round 6
// baseline (354.001 us; speedup 1.0000x reference)
//
#include <hip/hip_runtime.h>
#include <math.h>

typedef __bf16 bf16;
typedef __attribute__((ext_vector_type(8))) __bf16 bf16x8;
typedef __attribute__((ext_vector_type(4))) __bf16 bf16x4;
typedef __attribute__((ext_vector_type(4))) float f32x4;

#define NTOK 4096
#define DM   1024
#define NE   8      // routed experts
#define NEX  10     // + 2 shared halves (identity-routed)
#define HE   704

#define MAP1_CAP 224   // per-XCD slot cap, gemm1 (total 1792 blocks)
#define MAP2_CAP 160   // per-XCD slot cap, gemm2 (total 1280 blocks)

// ---------------- workspace layout (bytes) — high-water ~75 MB ----------
#define OFF_CNT   0u            // cnt[8]; pfx[13] at +32
#define OFF_TOK   256u          // [8][4096] int
#define OFF_WGT   131328u       // [8][4096] float
#define OFF_XB    262400u       // [4096][1024] bf16 row-major
#define OFF_W1T   8651008u      // [8] swizzled [44][32][64][8] bf16   (reused as yr after gemm1)
#define OFF_W3T   20185344u
#define OFF_W2T   31719680u     // [8] swizzled [64][22][64][8] bf16
#define OFF_WS1T  43254016u     // [2] swizzled [44][32][64][8]
#define OFF_WS3T  46137600u
#define OFF_WS2T  49021184u     // [2] swizzled [64][22][64][8]
#define OFF_ACT   51904768u     // [16384][704] bf16 row-major (pfx-compacted)
#define OFF_EIDS  74973440u     // [4096] int (dead after build_lists; reused for tile maps)
#define OFF_MAP1  OFF_EIDS      // [8*224] int XCD-pinned work list (slot*8+xcd)
#define OFF_MAP2  (OFF_EIDS + 8192u)  // [8*160] int
#define OFF_GW    74989824u     // [4096] float2
#define OFF_SLOT  75022592u     // [4096] int2  ((e<<16)|pos per routed assignment)
#define OFF_YR    OFF_W1T       // [8192][1024] bf16 routed weighted partials (aliases w1t/w3t)

// async global->LDS, 16 B/lane: HW dest = wave-uniform base + lane*16 (m104/m108).
__device__ __forceinline__ void async_cp16(const bf16* g, bf16* l)
{
    __builtin_amdgcn_global_load_lds(
        (const __attribute__((address_space(1))) unsigned int*)g,
        (__attribute__((address_space(3))) unsigned int*)l, 16, 0, 0);
}

// ---------------- x -> bf16 (row-major) ----------------
__global__ void cvt_x_kernel(const float* __restrict__ x, bf16* __restrict__ xb, int n4)
{
    int i = blockIdx.x * blockDim.x + threadIdx.x;
    if (i >= n4) return;
    float4 v = ((const float4*)x)[i];
    bf16x4 o;
    o[0] = (bf16)v.x; o[1] = (bf16)v.y; o[2] = (bf16)v.z; o[3] = (bf16)v.w;
    ((bf16x4*)xb)[i] = o;
}

// ---------------- weight transpose+convert -> fragment-swizzled 1KB blocks ----------------
__global__ __launch_bounds__(256) void transpose_all(
    const float* __restrict__ W1, const float* __restrict__ W3, const float* __restrict__ W2,
    const float* __restrict__ Ws1, const float* __restrict__ Ws3, const float* __restrict__ Ws2,
    bf16* __restrict__ w1t, bf16* __restrict__ w3t, bf16* __restrict__ w2t,
    bf16* __restrict__ ws1t, bf16* __restrict__ ws3t, bf16* __restrict__ ws2t)
{
    int id = blockIdx.x;
    const float* src; bf16* dst; int C, rt, ct, nkt;
    if (id < 5632)       { int t = id;         int e = t / 704, m = t % 704; C = 704;
                           src = W1 + (size_t)e * 1024 * 704;  dst = w1t + (size_t)e * 720896;
                           ct = m % 22; rt = m / 22; nkt = 32; }
    else if (id < 11264) { int t = id - 5632;  int e = t / 704, m = t % 704; C = 704;
                           src = W3 + (size_t)e * 1024 * 704;  dst = w3t + (size_t)e * 720896;
                           ct = m % 22; rt = m / 22; nkt = 32; }
    else if (id < 16896) { int t = id - 11264; int e = t / 704, m = t % 704; C = 1024;
                           src = W2 + (size_t)e * 704 * 1024;  dst = w2t + (size_t)e * 720896;
                           ct = m % 32; rt = m / 32; nkt = 22; }
    else if (id < 18304) { int t = id - 16896; C = 1408; src = Ws1;
                           ct = t % 44; rt = t / 44; nkt = 32;
                           int ep = (ct >= 22) ? 1 : 0; ct -= 22 * ep;
                           src += (size_t)704 * ep;
                           dst = ws1t + (size_t)ep * 720896; }
    else if (id < 19712) { int t = id - 18304; C = 1408; src = Ws3;
                           ct = t % 44; rt = t / 44; nkt = 32;
                           int ep = (ct >= 22) ? 1 : 0; ct -= 22 * ep;
                           src += (size_t)704 * ep;
                           dst = ws3t + (size_t)ep * 720896; }
    else                 { int t = id - 19712; C = 1024; src = Ws2;
                           ct = t % 32; rt = t / 32; nkt = 22;
                           int ep = (rt >= 22) ? 1 : 0; rt -= 22 * ep;
                           src += (size_t)704 * 1024 * ep;
                           dst = ws2t + (size_t)ep * 720896; }

    __shared__ float tl[32][33];
    int c0 = ct * 32, r0 = rt * 32;          // r = k dim, c = n dim (src [K][N] row-major)
    int row  = threadIdx.x >> 3;
    int col4 = (threadIdx.x & 7) * 4;
    float4 v = *(const float4*)&src[(size_t)(r0 + row) * C + c0 + col4];
    tl[row][col4 + 0] = v.x; tl[row][col4 + 1] = v.y;
    tl[row][col4 + 2] = v.z; tl[row][col4 + 3] = v.w;
    __syncthreads();
    int n  = c0 + row;
    int ng = n >> 4, nr = n & 15;
    int kt = rt;
    int cc = col4 >> 3, j = col4 & 7;
    bf16x4 o;
    o[0] = (bf16)tl[col4 + 0][row];
    o[1] = (bf16)tl[col4 + 1][row];
    o[2] = (bf16)tl[col4 + 2][row];
    o[3] = (bf16)tl[col4 + 3][row];
    *(bf16x4*)&dst[(size_t)(((ng * nkt + kt) << 9) + (((cc << 4) | nr) << 3) + j)] = o;
}

// ---------------- router pass 1: fp32 logits, softmax, top-2 per token ----------------
__global__ __launch_bounds__(256) void router_logits(
    const float* __restrict__ x, const float* __restrict__ Wg,
    int* __restrict__ eids, float2* __restrict__ gw)
{
    int n    = blockIdx.x * 4 + (threadIdx.x >> 6);
    int lane = threadIdx.x & 63;
    const float* xrow = x + (size_t)n * DM;
    float xr[16];
    #pragma unroll
    for (int j = 0; j < 16; j++) xr[j] = xrow[lane + 64 * j];
    float logit[NE];
    #pragma unroll
    for (int e = 0; e < NE; e++) {
        const float* wr = Wg + e * DM;
        float s = 0.f;
        #pragma unroll
        for (int j = 0; j < 16; j++) s += xr[j] * wr[lane + 64 * j];
        #pragma unroll
        for (int off = 32; off; off >>= 1) s += __shfl_xor(s, off, 64);
        logit[e] = s;
    }
    if (lane == 0) {
        int i0 = 0;
        #pragma unroll
        for (int e = 1; e < NE; e++) if (logit[e] > logit[i0]) i0 = e;
        int i1 = (i0 == 0) ? 1 : 0;
        #pragma unroll
        for (int e = 0; e < NE; e++) if (e != i0 && logit[e] > logit[i1]) i1 = e;
        float m = logit[0];
        #pragma unroll
        for (int e = 1; e < NE; e++) m = fmaxf(m, logit[e]);
        float denom = 0.f;
        #pragma unroll
        for (int e = 0; e < NE; e++) denom += expf(logit[e] - m);
        float g0 = expf(logit[i0] - m) / denom;
        float g1 = expf(logit[i1] - m) / denom;
        float inv = 1.f / (g0 + g1 + 1e-20f);
        eids[n] = i0 | (i1 << 16);
        gw[n] = make_float2(g0 * inv, g1 * inv);
    }
}

// ---------------- router pass 2: list build + per-token slot record ----------------
__global__ __launch_bounds__(128) void build_lists(
    const int* __restrict__ eids, const float2* __restrict__ gw,
    int* __restrict__ cnt, int* __restrict__ tok, float* __restrict__ wgt,
    int2* __restrict__ slots)
{
    __shared__ int lcnt[NE];
    __shared__ int gbase[NE];
    int t = threadIdx.x;
    int n = blockIdx.x * 128 + t;
    if (t < NE) lcnt[t] = 0;
    __syncthreads();
    int packed = eids[n];
    float2 w = gw[n];
    int e0 = packed & 0xffff, e1 = packed >> 16;
    int s0 = atomicAdd(&lcnt[e0], 1);
    int s1 = atomicAdd(&lcnt[e1], 1);
    __syncthreads();
    if (t < NE) gbase[t] = atomicAdd(&cnt[t], lcnt[t]);
    __syncthreads();
    int p0 = gbase[e0] + s0, p1 = gbase[e1] + s1;
    tok[e0 * NTOK + p0] = n; wgt[e0 * NTOK + p0] = w.x;
    tok[e1 * NTOK + p1] = n; wgt[e1 * NTOK + p1] = w.y;
    slots[n] = make_int2((e0 << 16) | p0, (e1 << 16) | p1);
}

// ---------------- prefix + XCD-pinned work lists ----------------
// hw blockIdx % 8 == XCD (round-robin dispatch). Per-XCD lists keep one
// expert's tiles contiguous on one XCD so its B-panel (<=2.9MB) lives in
// that XCD's 4MB L2 instead of thrashing across all 8.
// Greedy is WORK-weighted (K-steps), not slot-weighted: gemm2's shared
// slots are 44 steps vs routed 22 — slot-balance put 2x-work slots on a
// few XCDs (r5 regression: gemm2 critical path ~2x balanced).
// entry: (e<<20) | (mtile<<8) | xtile ; -1 = no-op slot.
__global__ void prefix_kernel(const int* __restrict__ cnt, int* __restrict__ pfx,
                              int* __restrict__ map1, int* __restrict__ map2)
{
    int t = threadIdx.x;
    for (int i = t; i < 8 * MAP1_CAP; i += 64) map1[i] = -1;
    for (int i = t; i < 8 * MAP2_CAP; i += 64) map2[i] = -1;
    __syncthreads();
    if (t != 0) return;
    int s = 0;
    for (int e = 0; e < NEX; e++) { pfx[e] = s; s += (e < NE) ? cnt[e] : NTOK; }
    pfx[NEX] = s;

    int ntl[NEX];
    int tot1 = 0;
    for (int e = 0; e < NEX; e++) {
        int c = (e < NE) ? cnt[e] : NTOK;
        ntl[e] = (c + 127) >> 7;
        tot1 += ntl[e];
    }
    // ---- gemm1: units of 11 h-blocks (uniform 32-step work); slot-balance OK ----
    {
        int len[8] = {0,0,0,0,0,0,0,0};
        int avg = (tot1 * 11 + 7) >> 3;
        int k = 0;
        for (int e = 0; e < NEX; e++) {
            k = 0;
            for (int q = 1; q < 8; q++) if (len[q] < len[k]) k = q;
            for (int tt = 0; tt < ntl[e]; tt++) {
                if (len[k] >= avg) {
                    k = 0;
                    for (int q = 1; q < 8; q++) if (len[q] < len[k]) k = q;
                }
                if (len[k] + 11 > MAP1_CAP) {              // defensive slot-cap
                    k = 0;
                    for (int q = 1; q < 8; q++) if (len[q] < len[k]) k = q;
                }
                for (int h = 0; h < 11; h++)
                    map1[(len[k] + h) * 8 + k] = (e << 20) | (tt << 8) | h;
                len[k] += 11;
            }
        }
    }
    // ---- gemm2: units of 8 d-blocks; WORK-weighted (routed=22, shared=44/slot) ----
    {
        int wrk[8] = {0,0,0,0,0,0,0,0};
        int slt[8] = {0,0,0,0,0,0,0,0};
        int totw = 0;
        for (int e = 0; e <= NE; e++)
            totw += (e < NE) ? ntl[e] * 8 * 22 : (NTOK >> 7) * 8 * 44;
        int avg = (totw + 7) >> 3;
        int k = 0;
        for (int e = 0; e <= NE; e++) {
            int nt2 = (e < NE) ? ntl[e] : (NTOK >> 7);
            int wpd = (e < NE) ? 22 : 44;                  // work per d-slot
            k = 0;
            for (int q = 1; q < 8; q++) if (wrk[q] < wrk[k]) k = q;
            for (int tt = 0; tt < nt2; tt++) {
                if (wrk[k] >= avg) {
                    k = 0;
                    for (int q = 1; q < 8; q++) if (wrk[q] < wrk[k]) k = q;
                }
                if (slt[k] + 8 > MAP2_CAP) {               // defensive slot-cap
                    k = 0;
                    for (int q = 1; q < 8; q++) if (slt[q] < slt[k]) k = q;
                }
                for (int d = 0; d < 8; d++)
                    map2[(slt[k] + d) * 8 + k] = (e << 20) | (tt << 8) | d;
                slt[k] += 8;
                wrk[k] += 8 * wpd;
            }
        }
    }
}

// ---------------- GEMM1: act = silu(A@W1) * (A@W3) ---------------------------------
// Triple-buffered, single raw barrier per K-step, counted vmcnt (never 0 in steady
// state): loads issued at step t complete during steps t..t+1, hidden under MFMA.
__global__ __launch_bounds__(256) void gemm1_swiglu(
    const bf16* __restrict__ xb,
    const bf16* __restrict__ w1t, const bf16* __restrict__ w3t,
    const bf16* __restrict__ ws1t, const bf16* __restrict__ ws3t,
    bf16* __restrict__ act,
    const int* __restrict__ cnt, const int* __restrict__ pfx,
    const int* __restrict__ tok, const int* __restrict__ map)
{
    int b = blockIdx.x;
    int ent = map[(b >> 3) * 8 + (b & 7)];
    if (ent < 0) return;
    int e  = ent >> 20;
    int m0 = ((ent >> 8) & 0xfff) << 7;
    int h0 = (ent & 255) * 64;
    int count = (e < NE) ? cnt[e] : NTOK;
    int base = pfx[e];
    const bf16 *B1, *B3;
    if (e < NE) { B1 = w1t + (size_t)e * 720896;         B3 = w3t + (size_t)e * 720896; }
    else        { B1 = ws1t + (size_t)(e - NE) * 720896; B3 = ws3t + (size_t)(e - NE) * 720896; }
    const int* tlist = (e < NE) ? tok + e * NTOK : nullptr;

    __shared__ bf16 As[3][8 * 512];     // 24 KB
    __shared__ bf16 B1s[3][4 * 512];    // 12 KB
    __shared__ bf16 B3s[3][4 * 512];    // 12 KB  -> 48 KB total, 3 blocks/CU

    int tid = threadIdx.x, w = tid >> 6, lane = tid & 63;

    int r3 = lane >> 2;
    int cx = (lane & 3) ^ ((r3 >> 1) & 3);
    int sA0 = m0 + 32 * w + r3, sA1 = sA0 + 16;
    int rA0 = tlist ? (sA0 < count ? tlist[sA0] : 0) : (sA0 < count ? sA0 : 0);
    int rA1 = tlist ? (sA1 < count ? tlist[sA1] : 0) : (sA1 < count ? sA1 : 0);
    const bf16* ga0 = xb + (size_t)rA0 * DM + cx * 8;
    const bf16* ga1 = xb + (size_t)rA1 * DM + cx * 8;
    const bf16* gb1 = B1 + ((size_t)((h0 >> 4) + w) * 32) * 512 + lane * 8;
    const bf16* gb3 = B3 + ((size_t)((h0 >> 4) + w) * 32) * 512 + lane * 8;
    bf16* aA0 = &As[0][0]  + (2 * w) * 512;
    bf16* aA1 = aA0 + 512;
    bf16* aB1 = &B1s[0][0] + w * 512;
    bf16* aB3 = &B3s[0][0] + w * 512;

    int rl = lane & 15, ch = lane >> 4;
    int uA = 4 * rl + (ch ^ ((rl >> 1) & 3));
    int gA = (w & 1) * 4;
    int gB = (w >> 1) * 2;
    int wm = (w & 1) * 64, wn = (w >> 1) * 32;

    f32x4 acch[4][2], accg[4][2];
    #pragma unroll
    for (int i = 0; i < 4; i++)
        #pragma unroll
        for (int j = 0; j < 2; j++) {
            acch[i][j] = (f32x4){0.f, 0.f, 0.f, 0.f};
            accg[i][j] = (f32x4){0.f, 0.f, 0.f, 0.f};
        }

#define STAGE1(bs) do { \
        async_cp16(ga0, aA0 + (bs) * 4096); \
        async_cp16(ga1, aA1 + (bs) * 4096); \
        async_cp16(gb1, aB1 + (bs) * 2048); \
        async_cp16(gb3, aB3 + (bs) * 2048); \
        ga0 += 32; ga1 += 32; gb1 += 512; gb3 += 512; \
    } while (0)

    STAGE1(0);                                           // tile 0 (4 loads in flight)
    STAGE1(1);                                           // tile 1 (8 in flight)
    asm volatile("s_waitcnt vmcnt(4)" ::: "memory");     // tile 0 complete
    __builtin_amdgcn_s_barrier();

    int rb = 0, sb = 2;
    for (int k0 = 0; k0 < 32; k0++) {
        const bf16* Ab  = &As[0][0]  + rb * 4096;
        const bf16* B1b = &B1s[0][0] + rb * 2048;
        const bf16* B3b = &B3s[0][0] + rb * 2048;
        bf16x8 af[4], b1f[2], b3f[2];
        #pragma unroll
        for (int i = 0; i < 4; i++) af[i] = *(const bf16x8*)(Ab + (gA + i) * 512 + uA * 8);
        #pragma unroll
        for (int j = 0; j < 2; j++) {
            b1f[j] = *(const bf16x8*)(B1b + (gB + j) * 512 + lane * 8);
            b3f[j] = *(const bf16x8*)(B3b + (gB + j) * 512 + lane * 8);
        }
        if (k0 < 30) STAGE1(sb);                         // stage tile k0+2
        #pragma unroll
        for (int i = 0; i < 4; i++)
            #pragma unroll
            for (int j = 0; j < 2; j++) {
                acch[i][j] = __builtin_amdgcn_mfma_f32_16x16x32_bf16(af[i], b1f[j], acch[i][j], 0, 0, 0);
                accg[i][j] = __builtin_amdgcn_mfma_f32_16x16x32_bf16(af[i], b3f[j], accg[i][j], 0, 0, 0);
            }
        if (k0 < 30)       asm volatile("s_waitcnt vmcnt(4)" ::: "memory"); // tile k0+1 ready
        else if (k0 == 30) asm volatile("s_waitcnt vmcnt(0)" ::: "memory"); // last tile ready
        __builtin_amdgcn_sched_barrier(0);
        __builtin_amdgcn_s_barrier();
        rb = (rb == 2) ? 0 : rb + 1;
        sb = (sb == 2) ? 0 : sb + 1;
    }
#undef STAGE1

    #pragma unroll
    for (int i = 0; i < 4; i++)
        #pragma unroll
        for (int j = 0; j < 2; j++)
            #pragma unroll
            for (int r = 0; r < 4; r++) {
                int row = wm + i * 16 + ch * 4 + r;
                int s2 = m0 + row;
                if (s2 < count) {
                    float hv = acch[i][j][r], gv = accg[i][j][r];
                    float a = hv / (1.f + expf(-hv)) * gv;
                    act[(size_t)(base + s2) * HE + h0 + wn + j * 16 + rl] = (bf16)a;
                }
            }
}

// ---------------- GEMM2 unified (routed + shared), triple-buffered counted-vmcnt ------
// e<8 : yr[slot] = bf16(gate * act@W2)   (22 K-steps)
// e==8: out[n]   = act_sh @ Ws2, K=1408 via two 22-step segments, fp32 plain stores
__global__ __launch_bounds__(256) void gemm2_all(
    const bf16* __restrict__ act,
    const bf16* __restrict__ w2t, const bf16* __restrict__ ws2t,
    bf16* __restrict__ yr, float* __restrict__ out,
    const int* __restrict__ cnt, const int* __restrict__ pfx,
    const float* __restrict__ wgt, const int* __restrict__ map)
{
    int b = blockIdx.x;
    int ent = map[(b >> 3) * 8 + (b & 7)];
    if (ent < 0) return;
    int e  = ent >> 20;
    int m0 = ((ent >> 8) & 0xfff) << 7;
    int d0 = (ent & 255) * 128;

    __shared__ bf16 As[3][8 * 512];     // 24 KB
    __shared__ bf16 Bs[3][8 * 512];     // 24 KB -> 48 KB total

    int tid = threadIdx.x, w = tid >> 6, lane = tid & 63;

    int r3 = lane >> 2;
    int cx = (lane & 3) ^ ((r3 >> 1) & 3);
    int sA0 = m0 + 32 * w + r3, sA1 = sA0 + 16;
    int rl = lane & 15, ch = lane >> 4;
    int uA = 4 * rl + (ch ^ ((rl >> 1) & 3));
    int gA = (w & 1) * 4, gB = (w >> 1) * 4;
    int wm = (w & 1) * 64, wn = (w >> 1) * 64;

    bf16* aA0 = &As[0][0] + (2 * w) * 512;
    bf16* aA1 = aA0 + 512;
    bf16* aB0 = &Bs[0][0] + (2 * w) * 512;
    bf16* aB1 = aB0 + 512;

    int count, base; const bf16* Bp;
    if (e < NE) { count = cnt[e]; base = pfx[e]; Bp = w2t + (size_t)e * 720896; }
    else        { count = NTOK;   base = NTOK * 2; Bp = ws2t; }   // pfx[8]==8192 always

    int a0 = (sA0 < count) ? (base + sA0) : base;
    int a1 = (sA1 < count) ? (base + sA1) : base;
    const bf16* ga0 = act + (size_t)a0 * HE + cx * 8;
    const bf16* ga1 = act + (size_t)a1 * HE + cx * 8;
    const bf16* gb0 = Bp + ((size_t)((d0 >> 4) + 2 * w) * 22) * 512 + lane * 8;
    const bf16* gb1 = Bp + ((size_t)((d0 >> 4) + 2 * w + 1) * 22) * 512 + lane * 8;

    f32x4 acc[4][4];
    #pragma unroll
    for (int i = 0; i < 4; i++)
        #pragma unroll
        for (int j = 0; j < 4; j++) acc[i][j] = (f32x4){0.f, 0.f, 0.f, 0.f};

#define STAGE2(bs) do { \
        async_cp16(ga0, aA0 + (bs) * 4096); \
        async_cp16(ga1, aA1 + (bs) * 4096); \
        async_cp16(gb0, aB0 + (bs) * 4096); \
        async_cp16(gb1, aB1 + (bs) * 4096); \
        ga0 += 32; ga1 += 32; gb0 += 512; gb1 += 512; \
    } while (0)

    int total = (e < NE) ? 22 : 44;
    STAGE2(0);
    STAGE2(1);
    asm volatile("s_waitcnt vmcnt(4)" ::: "memory");
    __builtin_amdgcn_s_barrier();

    int rb = 0, sb = 2;
    for (int kt = 0; kt < total; kt++) {
        const bf16* Ab = &As[0][0] + rb * 4096;
        const bf16* Bb = &Bs[0][0] + rb * 4096;
        bf16x8 af[4], bf_[4];
        #pragma unroll
        for (int i = 0; i < 4; i++) af[i]  = *(const bf16x8*)(Ab + (gA + i) * 512 + uA * 8);
        #pragma unroll
        for (int j = 0; j < 4; j++) bf_[j] = *(const bf16x8*)(Bb + (gB + j) * 512 + lane * 8);
        int nx = kt + 2;
        if (nx < total) {
            if (nx == 22) {                 // only when total==44: switch to shared half 1
                ga0 = act + (size_t)(12288 + sA0) * HE + cx * 8;   // pfx[9]==12288 always
                ga1 = act + (size_t)(12288 + sA1) * HE + cx * 8;
                const bf16* B2 = ws2t + 720896;
                gb0 = B2 + ((size_t)((d0 >> 4) + 2 * w) * 22) * 512 + lane * 8;
                gb1 = B2 + ((size_t)((d0 >> 4) + 2 * w + 1) * 22) * 512 + lane * 8;
            }
            STAGE2(sb);
        }
        #pragma unroll
        for (int i = 0; i < 4; i++)
            #pragma unroll
            for (int j = 0; j < 4; j++)
                acc[i][j] = __builtin_amdgcn_mfma_f32_16x16x32_bf16(af[i], bf_[j], acc[i][j], 0, 0, 0);
        if (nx < total)       asm volatile("s_waitcnt vmcnt(4)" ::: "memory");
        else if (nx == total) asm volatile("s_waitcnt vmcnt(0)" ::: "memory");
        __builtin_amdgcn_sched_barrier(0);
        __builtin_amdgcn_s_barrier();
        rb = (rb == 2) ? 0 : rb + 1;
        sb = (sb == 2) ? 0 : sb + 1;
    }
#undef STAGE2

    if (e < NE) {
        const float* wl = wgt + e * NTOK;
        #pragma unroll
        for (int i = 0; i < 4; i++) {
            #pragma unroll
            for (int r = 0; r < 4; r++) {
                int row = wm + i * 16 + ch * 4 + r;
                int s2 = m0 + row;
                if (s2 < count) {
                    float wt = wl[s2];
                    bf16* yrow = yr + (size_t)(base + s2) * DM + d0 + wn;
                    #pragma unroll
                    for (int j = 0; j < 4; j++)
                        yrow[j * 16 + rl] = (bf16)(wt * acc[i][j][r]);
                }
            }
        }
    } else {
        #pragma unroll
        for (int i = 0; i < 4; i++) {
            #pragma unroll
            for (int r = 0; r < 4; r++) {
                int row = wm + i * 16 + ch * 4 + r;
                float* orow = out + (size_t)(m0 + row) * DM + d0 + wn;
                #pragma unroll
                for (int j = 0; j < 4; j++)
                    orow[j * 16 + rl] = acc[i][j][r];
            }
        }
    }
}

// ---------------- fuse: out[n] += yr[slot0] + yr[slot1] ----------------
__global__ __launch_bounds__(256) void fuse_add(
    const bf16* __restrict__ yr, const int2* __restrict__ slots,
    const int* __restrict__ pfx, float* __restrict__ out)
{
    int n = blockIdx.x;
    int2 s = slots[n];
    int slot0 = pfx[s.x >> 16] + (s.x & 0xffff);
    int slot1 = pfx[s.y >> 16] + (s.y & 0xffff);
    const bf16* y0 = yr + (size_t)slot0 * DM;
    const bf16* y1 = yr + (size_t)slot1 * DM;
    float* orow = out + (size_t)n * DM;
    int d = threadIdx.x * 4;
    bf16x4 a = *(const bf16x4*)(y0 + d);
    bf16x4 b = *(const bf16x4*)(y1 + d);
    float4 o = *(float4*)(orow + d);
    o.x += (float)a[0] + (float)b[0];
    o.y += (float)a[1] + (float)b[1];
    o.z += (float)a[2] + (float)b[2];
    o.w += (float)a[3] + (float)b[3];
    *(float4*)(orow + d) = o;
}

extern "C" void kernel_launch(void* const* d_in, const int* in_sizes, int n_in,
                              void* d_out, int out_size, void* d_ws, size_t ws_size,
                              hipStream_t stream)
{
    const float* x   = (const float*)d_in[0];
    const float* Wg  = (const float*)d_in[1];
    const float* W1  = (const float*)d_in[2];
    const float* W3  = (const float*)d_in[3];
    const float* W2  = (const float*)d_in[4];
    const float* Ws1 = (const float*)d_in[5];
    const float* Ws3 = (const float*)d_in[6];
    const float* Ws2 = (const float*)d_in[7];
    float* out = (float*)d_out;
    char*  ws  = (char*)d_ws;

    int*    cnt   = (int*)(ws + OFF_CNT);
    int*    pfx   = (int*)(ws + OFF_CNT + 32);
    int*    tok   = (int*)(ws + OFF_TOK);
    float*  wgt   = (float*)(ws + OFF_WGT);
    bf16*   xb    = (bf16*)(ws + OFF_XB);
    bf16*   w1t   = (bf16*)(ws + OFF_W1T);
    bf16*   w3t   = (bf16*)(ws + OFF_W3T);
    bf16*   w2t   = (bf16*)(ws + OFF_W2T);
    bf16*   ws1t  = (bf16*)(ws + OFF_WS1T);
    bf16*   ws3t  = (bf16*)(ws + OFF_WS3T);
    bf16*   ws2t  = (bf16*)(ws + OFF_WS2T);
    bf16*   act   = (bf16*)(ws + OFF_ACT);
    int*    eids  = (int*)(ws + OFF_EIDS);
    int*    map1  = (int*)(ws + OFF_MAP1);   // aliases eids (dead after build_lists)
    int*    map2  = (int*)(ws + OFF_MAP2);
    float2* gw    = (float2*)(ws + OFF_GW);
    int2*   slots = (int2*)(ws + OFF_SLOT);
    bf16*   yr    = (bf16*)(ws + OFF_YR);    // aliases w1t/w3t (dead after gemm1)

    hipMemsetAsync(ws, 0, 256, stream);

    cvt_x_kernel<<<4096, 256, 0, stream>>>(x, xb, NTOK * DM / 4);
    transpose_all<<<21120, 256, 0, stream>>>(W1, W3, W2, Ws1, Ws3, Ws2,
                                             w1t, w3t, w2t, ws1t, ws3t, ws2t);
    router_logits<<<1024, 256, 0, stream>>>(x, Wg, eids, gw);
    build_lists<<<32, 128, 0, stream>>>(eids, gw, cnt, tok, wgt, slots);
    prefix_kernel<<<1, 64, 0, stream>>>(cnt, pfx, map1, map2);

    // XCD-pinned 1D grids (blockIdx%8 -> XCD; map holds per-XCD lists)
    gemm1_swiglu<<<8 * MAP1_CAP, 256, 0, stream>>>(
        xb, w1t, w3t, ws1t, ws3t, act, cnt, pfx, tok, map1);

    gemm2_all<<<8 * MAP2_CAP, 256, 0, stream>>>(
        act, w2t, ws2t, yr, out, cnt, pfx, wgt, map2);

    fuse_add<<<NTOK, 256, 0, stream>>>(yr, slots, pfx, out);
}

// Round 7
// 313.130 us; speedup vs baseline: 1.1305x; 1.1305x over previous
//
#include <hip/hip_runtime.h>
#include <math.h>

typedef __bf16 bf16;
typedef __attribute__((ext_vector_type(8))) __bf16 bf16x8;
typedef __attribute__((ext_vector_type(4))) __bf16 bf16x4;
typedef __attribute__((ext_vector_type(4))) float f32x4;

#define NTOK 4096
#define DM   1024
#define NE   8      // routed experts
#define NEX  10     // + 2 shared halves (identity-routed)
#define HE   704

#define MAP1_CAP 224   // per-XCD slot cap, gemm1 (total 1792 blocks)
#define MAP2_CAP 160   // per-XCD slot cap, gemm2 (total 1280 blocks)

// ---------------- workspace layout (bytes) — high-water ~75 MB ----------
#define OFF_CNT   0u            // cnt[8]; pfx[13] at +32
#define OFF_TOK   256u          // [8][4096] int
#define OFF_WGT   131328u       // [8][4096] float
#define OFF_XB    262400u       // [4096][1024] bf16 row-major
#define OFF_W1T   8651008u      // [8] swizzled [44][32][64][8] bf16   (reused as yr after gemm1)
#define OFF_W3T   20185344u
#define OFF_W2T   31719680u     // [8] swizzled [64][22][64][8] bf16
#define OFF_WS1T  43254016u     // [2] swizzled [44][32][64][8]
#define OFF_WS3T  46137600u
#define OFF_WS2T  49021184u     // [2] swizzled [64][22][64][8]
#define OFF_ACT   51904768u     // [16384][704] bf16 row-major (pfx-compacted)
#define OFF_EIDS  74973440u     // [4096] int (dead after build_lists; reused for tile maps)
#define OFF_MAP1  OFF_EIDS      // [8*224] int XCD-pinned work list (slot*8+xcd)
#define OFF_MAP2  (OFF_EIDS + 8192u)  // [8*160] int
#define OFF_GW    74989824u     // [4096] float2
#define OFF_SLOT  75022592u     // [4096] int2  ((e<<16)|pos per routed assignment)
#define OFF_YR    OFF_W1T       // [8192][1024] bf16 routed weighted partials (aliases w1t/w3t)

// async global->LDS, 16 B/lane: HW dest = wave-uniform base + lane*16 (m104/m108).
__device__ __forceinline__ void async_cp16(const bf16* g, bf16* l)
{
    __builtin_amdgcn_global_load_lds(
        (const __attribute__((address_space(1))) unsigned int*)g,
        (__attribute__((address_space(3))) unsigned int*)l, 16, 0, 0);
}

// ---------------- x -> bf16 (row-major) ----------------
__global__ void cvt_x_kernel(const float* __restrict__ x, bf16* __restrict__ xb, int n4)
{
    int i = blockIdx.x * blockDim.x + threadIdx.x;
    if (i >= n4) return;
    float4 v = ((const float4*)x)[i];
    bf16x4 o;
    o[0] = (bf16)v.x; o[1] = (bf16)v.y; o[2] = (bf16)v.z; o[3] = (bf16)v.w;
    ((bf16x4*)xb)[i] = o;
}

// ---------------- weight transpose+convert -> fragment-swizzled 1KB blocks ----------------
__global__ __launch_bounds__(256) void transpose_all(
    const float* __restrict__ W1, const float* __restrict__ W3, const float* __restrict__ W2,
    const float* __restrict__ Ws1, const float* __restrict__ Ws3, const float* __restrict__ Ws2,
    bf16* __restrict__ w1t, bf16* __restrict__ w3t, bf16* __restrict__ w2t,
    bf16* __restrict__ ws1t, bf16* __restrict__ ws3t, bf16* __restrict__ ws2t)
{
    int id = blockIdx.x;
    const float* src; bf16* dst; int C, rt, ct, nkt;
    if (id < 5632)       { int t = id;         int e = t / 704, m = t % 704; C = 704;
                           src = W1 + (size_t)e * 1024 * 704;  dst = w1t + (size_t)e * 720896;
                           ct = m % 22; rt = m / 22; nkt = 32; }
    else if (id < 11264) { int t = id - 5632;  int e = t / 704, m = t % 704; C = 704;
                           src = W3 + (size_t)e * 1024 * 704;  dst = w3t + (size_t)e * 720896;
                           ct = m % 22; rt = m / 22; nkt = 32; }
    else if (id < 16896) { int t = id - 11264; int e = t / 704, m = t % 704; C = 1024;
                           src = W2 + (size_t)e * 704 * 1024;  dst = w2t + (size_t)e * 720896;
                           ct = m % 32; rt = m / 32; nkt = 22; }
    else if (id < 18304) { int t = id - 16896; C = 1408; src = Ws1;
                           ct = t % 44; rt = t / 44; nkt = 32;
                           int ep = (ct >= 22) ? 1 : 0; ct -= 22 * ep;
                           src += (size_t)704 * ep;
                           dst = ws1t + (size_t)ep * 720896; }
    else if (id < 19712) { int t = id - 18304; C = 1408; src = Ws3;
                           ct = t % 44; rt = t / 44; nkt = 32;
                           int ep = (ct >= 22) ? 1 : 0; ct -= 22 * ep;
                           src += (size_t)704 * ep;
                           dst = ws3t + (size_t)ep * 720896; }
    else                 { int t = id - 19712; C = 1024; src = Ws2;
                           ct = t % 32; rt = t / 32; nkt = 22;
                           int ep = (rt >= 22) ? 1 : 0; rt -= 22 * ep;
                           src += (size_t)704 * 1024 * ep;
                           dst = ws2t + (size_t)ep * 720896; }

    __shared__ float tl[32][33];
    int c0 = ct * 32, r0 = rt * 32;          // r = k dim, c = n dim (src [K][N] row-major)
    int row  = threadIdx.x >> 3;
    int col4 = (threadIdx.x & 7) * 4;
    float4 v = *(const float4*)&src[(size_t)(r0 + row) * C + c0 + col4];
    tl[row][col4 + 0] = v.x; tl[row][col4 + 1] = v.y;
    tl[row][col4 + 2] = v.z; tl[row][col4 + 3] = v.w;
    __syncthreads();
    int n  = c0 + row;
    int ng = n >> 4, nr = n & 15;
    int kt = rt;
    int cc = col4 >> 3, j = col4 & 7;
    bf16x4 o;
    o[0] = (bf16)tl[col4 + 0][row];
    o[1] = (bf16)tl[col4 + 1][row];
    o[2] = (bf16)tl[col4 + 2][row];
    o[3] = (bf16)tl[col4 + 3][row];
    *(bf16x4*)&dst[(size_t)(((ng * nkt + kt) << 9) + (((cc << 4) | nr) << 3) + j)] = o;
}

// ---------------- router pass 1: fp32 logits, softmax, top-2 per token ----------------
__global__ __launch_bounds__(256) void router_logits(
    const float* __restrict__ x, const float* __restrict__ Wg,
    int* __restrict__ eids, float2* __restrict__ gw)
{
    int n    = blockIdx.x * 4 + (threadIdx.x >> 6);
    int lane = threadIdx.x & 63;
    const float* xrow = x + (size_t)n * DM;
    float xr[16];
    #pragma unroll
    for (int j = 0; j < 16; j++) xr[j] = xrow[lane + 64 * j];
    float logit[NE];
    #pragma unroll
    for (int e = 0; e < NE; e++) {
        const float* wr = Wg + e * DM;
        float s = 0.f;
        #pragma unroll
        for (int j = 0; j < 16; j++) s += xr[j] * wr[lane + 64 * j];
        #pragma unroll
        for (int off = 32; off; off >>= 1) s += __shfl_xor(s, off, 64);
        logit[e] = s;
    }
    if (lane == 0) {
        int i0 = 0;
        #pragma unroll
        for (int e = 1; e < NE; e++) if (logit[e] > logit[i0]) i0 = e;
        int i1 = (i0 == 0) ? 1 : 0;
        #pragma unroll
        for (int e = 0; e < NE; e++) if (e != i0 && logit[e] > logit[i1]) i1 = e;
        float m = logit[0];
        #pragma unroll
        for (int e = 1; e < NE; e++) m = fmaxf(m, logit[e]);
        float denom = 0.f;
        #pragma unroll
        for (int e = 0; e < NE; e++) denom += expf(logit[e] - m);
        float g0 = expf(logit[i0] - m) / denom;
        float g1 = expf(logit[i1] - m) / denom;
        float inv = 1.f / (g0 + g1 + 1e-20f);
        eids[n] = i0 | (i1 << 16);
        gw[n] = make_float2(g0 * inv, g1 * inv);
    }
}

// ---------------- router pass 2: list build + per-token slot record ----------------
__global__ __launch_bounds__(128) void build_lists(
    const int* __restrict__ eids, const float2* __restrict__ gw,
    int* __restrict__ cnt, int* __restrict__ tok, float* __restrict__ wgt,
    int2* __restrict__ slots)
{
    __shared__ int lcnt[NE];
    __shared__ int gbase[NE];
    int t = threadIdx.x;
    int n = blockIdx.x * 128 + t;
    if (t < NE) lcnt[t] = 0;
    __syncthreads();
    int packed = eids[n];
    float2 w = gw[n];
    int e0 = packed & 0xffff, e1 = packed >> 16;
    int s0 = atomicAdd(&lcnt[e0], 1);
    int s1 = atomicAdd(&lcnt[e1], 1);
    __syncthreads();
    if (t < NE) gbase[t] = atomicAdd(&cnt[t], lcnt[t]);
    __syncthreads();
    int p0 = gbase[e0] + s0, p1 = gbase[e1] + s1;
    tok[e0 * NTOK + p0] = n; wgt[e0 * NTOK + p0] = w.x;
    tok[e1 * NTOK + p1] = n; wgt[e1 * NTOK + p1] = w.y;
    slots[n] = make_int2((e0 << 16) | p0, (e1 << 16) | p1);
}

// ---------------- prefix + XCD-pinned work lists ----------------
// r6 post-mortem: single-thread greedy + serial map stores = 133us (top
// dispatch, whole GPU idle). Split: thread 0 makes per-TILE decisions only
// (~236 iters, LDS), then all 64 lanes expand to map entries in parallel.
// Greedy policy unchanged from r6 (work-weighted gemm2, run-based locality).
// entry: (e<<20) | (mtile<<8) | xtile ; -1 = no-op slot.
__global__ void prefix_kernel(const int* __restrict__ cnt, int* __restrict__ pfx,
                              int* __restrict__ map1, int* __restrict__ map2)
{
    __shared__ int sx1[144], ss1[144], se1[144];   // gemm1 segments (<=136)
    __shared__ int sx2[112], ss2[112], se2[112];   // gemm2 segments (<=104)
    __shared__ int ns1s, ns2s;
    int t = threadIdx.x;
    // parallel -1 init
    for (int i = t; i < 8 * MAP1_CAP; i += 64) map1[i] = -1;
    for (int i = t; i < 8 * MAP2_CAP; i += 64) map2[i] = -1;

    if (t == 0) {
        int s = 0;
        for (int e = 0; e < NEX; e++) { pfx[e] = s; s += (e < NE) ? cnt[e] : NTOK; }
        pfx[NEX] = s;

        int ntl[NEX];
        int tot1 = 0;
        for (int e = 0; e < NEX; e++) {
            int c = (e < NE) ? cnt[e] : NTOK;
            ntl[e] = (c + 127) >> 7;
            tot1 += ntl[e];
        }
        // ---- gemm1 decisions: units of 11 h-blocks; uniform work; slot-balance ----
        {
            int len[8] = {0,0,0,0,0,0,0,0};
            int avg = (tot1 * 11 + 7) >> 3;
            int ns = 0, k = 0;
            for (int e = 0; e < NEX; e++) {
                k = 0;
                for (int q = 1; q < 8; q++) if (len[q] < len[k]) k = q;
                for (int tt = 0; tt < ntl[e]; tt++) {
                    if (len[k] >= avg) {
                        k = 0;
                        for (int q = 1; q < 8; q++) if (len[q] < len[k]) k = q;
                    }
                    if (len[k] + 11 > MAP1_CAP) {
                        k = 0;
                        for (int q = 1; q < 8; q++) if (len[q] < len[k]) k = q;
                    }
                    sx1[ns] = k; ss1[ns] = len[k]; se1[ns] = (e << 20) | (tt << 8);
                    len[k] += 11; ns++;
                }
            }
            ns1s = ns;
        }
        // ---- gemm2 decisions: units of 8 d-blocks; WORK-weighted (22 vs 44) ----
        {
            int wrk[8] = {0,0,0,0,0,0,0,0};
            int slt[8] = {0,0,0,0,0,0,0,0};
            int totw = 0;
            for (int e = 0; e <= NE; e++)
                totw += (e < NE) ? ntl[e] * 8 * 22 : (NTOK >> 7) * 8 * 44;
            int avg = (totw + 7) >> 3;
            int ns = 0, k = 0;
            for (int e = 0; e <= NE; e++) {
                int nt2 = (e < NE) ? ntl[e] : (NTOK >> 7);
                int wpd = (e < NE) ? 22 : 44;
                k = 0;
                for (int q = 1; q < 8; q++) if (wrk[q] < wrk[k]) k = q;
                for (int tt = 0; tt < nt2; tt++) {
                    if (wrk[k] >= avg) {
                        k = 0;
                        for (int q = 1; q < 8; q++) if (wrk[q] < wrk[k]) k = q;
                    }
                    if (slt[k] + 8 > MAP2_CAP) {
                        k = 0;
                        for (int q = 1; q < 8; q++) if (slt[q] < slt[k]) k = q;
                    }
                    sx2[ns] = k; ss2[ns] = slt[k]; se2[ns] = (e << 20) | (tt << 8);
                    slt[k] += 8; wrk[k] += 8 * wpd; ns++;
                }
            }
            ns2s = ns;
        }
    }
    __syncthreads();
    // parallel expansion (addresses unique by construction)
    int n1 = ns1s, n2 = ns2s;
    for (int i = t; i < n1 * 11; i += 64) {
        int sg = i / 11, h = i - sg * 11;
        map1[(ss1[sg] + h) * 8 + sx1[sg]] = se1[sg] | h;
    }
    for (int i = t; i < n2 * 8; i += 64) {
        int sg = i >> 3, d = i & 7;
        map2[(ss2[sg] + d) * 8 + sx2[sg]] = se2[sg] | d;
    }
}

// ---------------- GEMM1: act = silu(A@W1) * (A@W3) ---------------------------------
// Triple-buffered, single raw barrier per K-step, counted vmcnt (never 0 in steady
// state): loads issued at step t complete during steps t..t+1, hidden under MFMA.
__global__ __launch_bounds__(256) void gemm1_swiglu(
    const bf16* __restrict__ xb,
    const bf16* __restrict__ w1t, const bf16* __restrict__ w3t,
    const bf16* __restrict__ ws1t, const bf16* __restrict__ ws3t,
    bf16* __restrict__ act,
    const int* __restrict__ cnt, const int* __restrict__ pfx,
    const int* __restrict__ tok, const int* __restrict__ map)
{
    int b = blockIdx.x;
    int ent = map[(b >> 3) * 8 + (b & 7)];
    if (ent < 0) return;
    int e  = ent >> 20;
    int m0 = ((ent >> 8) & 0xfff) << 7;
    int h0 = (ent & 255) * 64;
    int count = (e < NE) ? cnt[e] : NTOK;
    int base = pfx[e];
    const bf16 *B1, *B3;
    if (e < NE) { B1 = w1t + (size_t)e * 720896;         B3 = w3t + (size_t)e * 720896; }
    else        { B1 = ws1t + (size_t)(e - NE) * 720896; B3 = ws3t + (size_t)(e - NE) * 720896; }
    const int* tlist = (e < NE) ? tok + e * NTOK : nullptr;

    __shared__ bf16 As[3][8 * 512];     // 24 KB
    __shared__ bf16 B1s[3][4 * 512];    // 12 KB
    __shared__ bf16 B3s[3][4 * 512];    // 12 KB  -> 48 KB total, 3 blocks/CU

    int tid = threadIdx.x, w = tid >> 6, lane = tid & 63;

    int r3 = lane >> 2;
    int cx = (lane & 3) ^ ((r3 >> 1) & 3);
    int sA0 = m0 + 32 * w + r3, sA1 = sA0 + 16;
    int rA0 = tlist ? (sA0 < count ? tlist[sA0] : 0) : (sA0 < count ? sA0 : 0);
    int rA1 = tlist ? (sA1 < count ? tlist[sA1] : 0) : (sA1 < count ? sA1 : 0);
    const bf16* ga0 = xb + (size_t)rA0 * DM + cx * 8;
    const bf16* ga1 = xb + (size_t)rA1 * DM + cx * 8;
    const bf16* gb1 = B1 + ((size_t)((h0 >> 4) + w) * 32) * 512 + lane * 8;
    const bf16* gb3 = B3 + ((size_t)((h0 >> 4) + w) * 32) * 512 + lane * 8;
    bf16* aA0 = &As[0][0]  + (2 * w) * 512;
    bf16* aA1 = aA0 + 512;
    bf16* aB1 = &B1s[0][0] + w * 512;
    bf16* aB3 = &B3s[0][0] + w * 512;

    int rl = lane & 15, ch = lane >> 4;
    int uA = 4 * rl + (ch ^ ((rl >> 1) & 3));
    int gA = (w & 1) * 4;
    int gB = (w >> 1) * 2;
    int wm = (w & 1) * 64, wn = (w >> 1) * 32;

    f32x4 acch[4][2], accg[4][2];
    #pragma unroll
    for (int i = 0; i < 4; i++)
        #pragma unroll
        for (int j = 0; j < 2; j++) {
            acch[i][j] = (f32x4){0.f, 0.f, 0.f, 0.f};
            accg[i][j] = (f32x4){0.f, 0.f, 0.f, 0.f};
        }

#define STAGE1(bs) do { \
        async_cp16(ga0, aA0 + (bs) * 4096); \
        async_cp16(ga1, aA1 + (bs) * 4096); \
        async_cp16(gb1, aB1 + (bs) * 2048); \
        async_cp16(gb3, aB3 + (bs) * 2048); \
        ga0 += 32; ga1 += 32; gb1 += 512; gb3 += 512; \
    } while (0)

    STAGE1(0);                                           // tile 0 (4 loads in flight)
    STAGE1(1);                                           // tile 1 (8 in flight)
    asm volatile("s_waitcnt vmcnt(4)" ::: "memory");     // tile 0 complete
    __builtin_amdgcn_s_barrier();

    int rb = 0, sb = 2;
    for (int k0 = 0; k0 < 32; k0++) {
        const bf16* Ab  = &As[0][0]  + rb * 4096;
        const bf16* B1b = &B1s[0][0] + rb * 2048;
        const bf16* B3b = &B3s[0][0] + rb * 2048;
        bf16x8 af[4], b1f[2], b3f[2];
        #pragma unroll
        for (int i = 0; i < 4; i++) af[i] = *(const bf16x8*)(Ab + (gA + i) * 512 + uA * 8);
        #pragma unroll
        for (int j = 0; j < 2; j++) {
            b1f[j] = *(const bf16x8*)(B1b + (gB + j) * 512 + lane * 8);
            b3f[j] = *(const bf16x8*)(B3b + (gB + j) * 512 + lane * 8);
        }
        if (k0 < 30) STAGE1(sb);                         // stage tile k0+2
        #pragma unroll
        for (int i = 0; i < 4; i++)
            #pragma unroll
            for (int j = 0; j < 2; j++) {
                acch[i][j] = __builtin_amdgcn_mfma_f32_16x16x32_bf16(af[i], b1f[j], acch[i][j], 0, 0, 0);
                accg[i][j] = __builtin_amdgcn_mfma_f32_16x16x32_bf16(af[i], b3f[j], accg[i][j], 0, 0, 0);
            }
        if (k0 < 30)       asm volatile("s_waitcnt vmcnt(4)" ::: "memory"); // tile k0+1 ready
        else if (k0 == 30) asm volatile("s_waitcnt vmcnt(0)" ::: "memory"); // last tile ready
        __builtin_amdgcn_sched_barrier(0);
        __builtin_amdgcn_s_barrier();
        rb = (rb == 2) ? 0 : rb + 1;
        sb = (sb == 2) ? 0 : sb + 1;
    }
#undef STAGE1

    #pragma unroll
    for (int i = 0; i < 4; i++)
        #pragma unroll
        for (int j = 0; j < 2; j++)
            #pragma unroll
            for (int r = 0; r < 4; r++) {
                int row = wm + i * 16 + ch * 4 + r;
                int s2 = m0 + row;
                if (s2 < count) {
                    float hv = acch[i][j][r], gv = accg[i][j][r];
                    float a = hv / (1.f + expf(-hv)) * gv;
                    act[(size_t)(base + s2) * HE + h0 + wn + j * 16 + rl] = (bf16)a;
                }
            }
}

// ---------------- GEMM2 unified (routed + shared), triple-buffered counted-vmcnt ------
// e<8 : yr[slot] = bf16(gate * act@W2)   (22 K-steps)
// e==8: out[n]   = act_sh @ Ws2, K=1408 via two 22-step segments, fp32 plain stores
__global__ __launch_bounds__(256) void gemm2_all(
    const bf16* __restrict__ act,
    const bf16* __restrict__ w2t, const bf16* __restrict__ ws2t,
    bf16* __restrict__ yr, float* __restrict__ out,
    const int* __restrict__ cnt, const int* __restrict__ pfx,
    const float* __restrict__ wgt, const int* __restrict__ map)
{
    int b = blockIdx.x;
    int ent = map[(b >> 3) * 8 + (b & 7)];
    if (ent < 0) return;
    int e  = ent >> 20;
    int m0 = ((ent >> 8) & 0xfff) << 7;
    int d0 = (ent & 255) * 128;

    __shared__ bf16 As[3][8 * 512];     // 24 KB
    __shared__ bf16 Bs[3][8 * 512];     // 24 KB -> 48 KB total

    int tid = threadIdx.x, w = tid >> 6, lane = tid & 63;

    int r3 = lane >> 2;
    int cx = (lane & 3) ^ ((r3 >> 1) & 3);
    int sA0 = m0 + 32 * w + r3, sA1 = sA0 + 16;
    int rl = lane & 15, ch = lane >> 4;
    int uA = 4 * rl + (ch ^ ((rl >> 1) & 3));
    int gA = (w & 1) * 4, gB = (w >> 1) * 4;
    int wm = (w & 1) * 64, wn = (w >> 1) * 64;

    bf16* aA0 = &As[0][0] + (2 * w) * 512;
    bf16* aA1 = aA0 + 512;
    bf16* aB0 = &Bs[0][0] + (2 * w) * 512;
    bf16* aB1 = aB0 + 512;

    int count, base; const bf16* Bp;
    if (e < NE) { count = cnt[e]; base = pfx[e]; Bp = w2t + (size_t)e * 720896; }
    else        { count = NTOK;   base = NTOK * 2; Bp = ws2t; }   // pfx[8]==8192 always

    int a0 = (sA0 < count) ? (base + sA0) : base;
    int a1 = (sA1 < count) ? (base + sA1) : base;
    const bf16* ga0 = act + (size_t)a0 * HE + cx * 8;
    const bf16* ga1 = act + (size_t)a1 * HE + cx * 8;
    const bf16* gb0 = Bp + ((size_t)((d0 >> 4) + 2 * w) * 22) * 512 + lane * 8;
    const bf16* gb1 = Bp + ((size_t)((d0 >> 4) + 2 * w + 1) * 22) * 512 + lane * 8;

    f32x4 acc[4][4];
    #pragma unroll
    for (int i = 0; i < 4; i++)
        #pragma unroll
        for (int j = 0; j < 4; j++) acc[i][j] = (f32x4){0.f, 0.f, 0.f, 0.f};

#define STAGE2(bs) do { \
        async_cp16(ga0, aA0 + (bs) * 4096); \
        async_cp16(ga1, aA1 + (bs) * 4096); \
        async_cp16(gb0, aB0 + (bs) * 4096); \
        async_cp16(gb1, aB1 + (bs) * 4096); \
        ga0 += 32; ga1 += 32; gb0 += 512; gb1 += 512; \
    } while (0)

    int total = (e < NE) ? 22 : 44;
    STAGE2(0);
    STAGE2(1);
    asm volatile("s_waitcnt vmcnt(4)" ::: "memory");
    __builtin_amdgcn_s_barrier();

    int rb = 0, sb = 2;
    for (int kt = 0; kt < total; kt++) {
        const bf16* Ab = &As[0][0] + rb * 4096;
        const bf16* Bb = &Bs[0][0] + rb * 4096;
        bf16x8 af[4], bf_[4];
        #pragma unroll
        for (int i = 0; i < 4; i++) af[i]  = *(const bf16x8*)(Ab + (gA + i) * 512 + uA * 8);
        #pragma unroll
        for (int j = 0; j < 4; j++) bf_[j] = *(const bf16x8*)(Bb + (gB + j) * 512 + lane * 8);
        int nx = kt + 2;
        if (nx < total) {
            if (nx == 22) {                 // only when total==44: switch to shared half 1
                ga0 = act + (size_t)(12288 + sA0) * HE + cx * 8;   // pfx[9]==12288 always
                ga1 = act + (size_t)(12288 + sA1) * HE + cx * 8;
                const bf16* B2 = ws2t + 720896;
                gb0 = B2 + ((size_t)((d0 >> 4) + 2 * w) * 22) * 512 + lane * 8;
                gb1 = B2 + ((size_t)((d0 >> 4) + 2 * w + 1) * 22) * 512 + lane * 8;
            }
            STAGE2(sb);
        }
        #pragma unroll
        for (int i = 0; i < 4; i++)
            #pragma unroll
            for (int j = 0; j < 4; j++)
                acc[i][j] = __builtin_amdgcn_mfma_f32_16x16x32_bf16(af[i], bf_[j], acc[i][j], 0, 0, 0);
        if (nx < total)       asm volatile("s_waitcnt vmcnt(4)" ::: "memory");
        else if (nx == total) asm volatile("s_waitcnt vmcnt(0)" ::: "memory");
        __builtin_amdgcn_sched_barrier(0);
        __builtin_amdgcn_s_barrier();
        rb = (rb == 2) ? 0 : rb + 1;
        sb = (sb == 2) ? 0 : sb + 1;
    }
#undef STAGE2

    if (e < NE) {
        const float* wl = wgt + e * NTOK;
        #pragma unroll
        for (int i = 0; i < 4; i++) {
            #pragma unroll
            for (int r = 0; r < 4; r++) {
                int row = wm + i * 16 + ch * 4 + r;
                int s2 = m0 + row;
                if (s2 < count) {
                    float wt = wl[s2];
                    bf16* yrow = yr + (size_t)(base + s2) * DM + d0 + wn;
                    #pragma unroll
                    for (int j = 0; j < 4; j++)
                        yrow[j * 16 + rl] = (bf16)(wt * acc[i][j][r]);
                }
            }
        }
    } else {
        #pragma unroll
        for (int i = 0; i < 4; i++) {
            #pragma unroll
            for (int r = 0; r < 4; r++) {
                int row = wm + i * 16 + ch * 4 + r;
                float* orow = out + (size_t)(m0 + row) * DM + d0 + wn;
                #pragma unroll
                for (int j = 0; j < 4; j++)
                    orow[j * 16 + rl] = acc[i][j][r];
            }
        }
    }
}

// ---------------- fuse: out[n] += yr[slot0] + yr[slot1] ----------------
__global__ __launch_bounds__(256) void fuse_add(
    const bf16* __restrict__ yr, const int2* __restrict__ slots,
    const int* __restrict__ pfx, float* __restrict__ out)
{
    int n = blockIdx.x;
    int2 s = slots[n];
    int slot0 = pfx[s.x >> 16] + (s.x & 0xffff);
    int slot1 = pfx[s.y >> 16] + (s.y & 0xffff);
    const bf16* y0 = yr + (size_t)slot0 * DM;
    const bf16* y1 = yr + (size_t)slot1 * DM;
    float* orow = out + (size_t)n * DM;
    int d = threadIdx.x * 4;
    bf16x4 a = *(const bf16x4*)(y0 + d);
    bf16x4 b = *(const bf16x4*)(y1 + d);
    float4 o = *(float4*)(orow + d);
    o.x += (float)a[0] + (float)b[0];
    o.y += (float)a[1] + (float)b[1];
    o.z += (float)a[2] + (float)b[2];
    o.w += (float)a[3] + (float)b[3];
    *(float4*)(orow + d) = o;
}

extern "C" void kernel_launch(void* const* d_in, const int* in_sizes, int n_in,
                              void* d_out, int out_size, void* d_ws, size_t ws_size,
                              hipStream_t stream)
{
    const float* x   = (const float*)d_in[0];
    const float* Wg  = (const float*)d_in[1];
    const float* W1  = (const float*)d_in[2];
    const float* W3  = (const float*)d_in[3];
    const float* W2  = (const float*)d_in[4];
    const float* Ws1 = (const float*)d_in[5];
    const float* Ws3 = (const float*)d_in[6];
    const float* Ws2 = (const float*)d_in[7];
    float* out = (float*)d_out;
    char*  ws  = (char*)d_ws;

    int*    cnt   = (int*)(ws + OFF_CNT);
    int*    pfx   = (int*)(ws + OFF_CNT + 32);
    int*    tok   = (int*)(ws + OFF_TOK);
    float*  wgt   = (float*)(ws + OFF_WGT);
    bf16*   xb    = (bf16*)(ws + OFF_XB);
    bf16*   w1t   = (bf16*)(ws + OFF_W1T);
    bf16*   w3t   = (bf16*)(ws + OFF_W3T);
    bf16*   w2t   = (bf16*)(ws + OFF_W2T);
    bf16*   ws1t  = (bf16*)(ws + OFF_WS1T);
    bf16*   ws3t  = (bf16*)(ws + OFF_WS3T);
    bf16*   ws2t  = (bf16*)(ws + OFF_WS2T);
    bf16*   act   = (bf16*)(ws + OFF_ACT);
    int*    eids  = (int*)(ws + OFF_EIDS);
    int*    map1  = (int*)(ws + OFF_MAP1);   // aliases eids (dead after build_lists)
    int*    map2  = (int*)(ws + OFF_MAP2);
    float2* gw    = (float2*)(ws + OFF_GW);
    int2*   slots = (int2*)(ws + OFF_SLOT);
    bf16*   yr    = (bf16*)(ws + OFF_YR);    // aliases w1t/w3t (dead after gemm1)

    hipMemsetAsync(ws, 0, 256, stream);

    cvt_x_kernel<<<4096, 256, 0, stream>>>(x, xb, NTOK * DM / 4);
    transpose_all<<<21120, 256, 0, stream>>>(W1, W3, W2, Ws1, Ws3, Ws2,
                                             w1t, w3t, w2t, ws1t, ws3t, ws2t);
    router_logits<<<1024, 256, 0, stream>>>(x, Wg, eids, gw);
    build_lists<<<32, 128, 0, stream>>>(eids, gw, cnt, tok, wgt, slots);
    prefix_kernel<<<1, 64, 0, stream>>>(cnt, pfx, map1, map2);

    // XCD-pinned 1D grids (blockIdx%8 -> XCD; map holds per-XCD lists)
    gemm1_swiglu<<<8 * MAP1_CAP, 256, 0, stream>>>(
        xb, w1t, w3t, ws1t, ws3t, act, cnt, pfx, tok, map1);

    gemm2_all<<<8 * MAP2_CAP, 256, 0, stream>>>(
        act, w2t, ws2t, yr, out, cnt, pfx, wgt, map2);

    fuse_add<<<NTOK, 256, 0, stream>>>(yr, slots, pfx, out);
}

// Round 8
// 308.626 us; speedup vs baseline: 1.1470x; 1.0146x over previous
//
#include <hip/hip_runtime.h>
#include <math.h>

typedef __bf16 bf16;
typedef __attribute__((ext_vector_type(8))) __bf16 bf16x8;
typedef __attribute__((ext_vector_type(4))) __bf16 bf16x4;
typedef __attribute__((ext_vector_type(4))) float f32x4;

#define NTOK 4096
#define DM   1024
#define NE   8      // routed experts
#define NEX  10     // + 2 shared halves (identity-routed)
#define HE   704

#define MAP1_CAP 224   // per-XCD slot cap, gemm1 (total 1792 blocks)
#define MAP2_CAP 160   // per-XCD slot cap, gemm2 (total 1280 blocks)

// ---------------- workspace layout (bytes) — high-water ~75 MB ----------
#define OFF_CNT   0u            // cnt[8]; pfx[13] at +32
#define OFF_TOK   256u          // [8][4096] int
#define OFF_WGT   131328u       // [8][4096] float
#define OFF_XB    262400u       // [4096][1024] bf16 row-major
#define OFF_W1T   8651008u      // [8] swizzled [44][32][64][8] bf16   (reused as yr after gemm1)
#define OFF_W3T   20185344u
#define OFF_W2T   31719680u     // [8] swizzled [64][22][64][8] bf16
#define OFF_WS1T  43254016u     // [2] swizzled [44][32][64][8]
#define OFF_WS3T  46137600u
#define OFF_WS2T  49021184u     // [2] swizzled [64][22][64][8]
#define OFF_ACT   51904768u     // [16384][704] bf16 row-major (pfx-compacted)
#define OFF_EIDS  74973440u     // [4096] int (dead after build_lists; reused for tile maps)
#define OFF_MAP1  OFF_EIDS      // [8*224] int XCD-pinned work list (slot*8+xcd)
#define OFF_MAP2  (OFF_EIDS + 8192u)  // [8*160] int
#define OFF_GW    74989824u     // [4096] float2
#define OFF_SLOT  75022592u     // [4096] int2  ((e<<16)|pos per routed assignment)
#define OFF_YR    OFF_W1T       // [8192][1024] bf16 routed weighted partials (aliases w1t/w3t)

// async global->LDS, 16 B/lane: HW dest = wave-uniform base + lane*16 (m104/m108).
__device__ __forceinline__ void async_cp16(const bf16* g, bf16* l)
{
    __builtin_amdgcn_global_load_lds(
        (const __attribute__((address_space(1))) unsigned int*)g,
        (__attribute__((address_space(3))) unsigned int*)l, 16, 0, 0);
}

// ---------------- fused prep: weight transpose (coalesced) + x->bf16 + router ------
// blocks [0, 21120)            : weight transpose/convert -> swizzled 1KB blocks
// blocks [21120, 21120+4096)   : x -> bf16 row-major
// blocks [25216, 25216+1024)   : router logits + softmax + top2
__global__ __launch_bounds__(256) void prep_all(
    const float* __restrict__ x,  const float* __restrict__ Wg,
    const float* __restrict__ W1, const float* __restrict__ W3, const float* __restrict__ W2,
    const float* __restrict__ Ws1, const float* __restrict__ Ws3, const float* __restrict__ Ws2,
    bf16* __restrict__ w1t, bf16* __restrict__ w3t, bf16* __restrict__ w2t,
    bf16* __restrict__ ws1t, bf16* __restrict__ ws3t, bf16* __restrict__ ws2t,
    bf16* __restrict__ xb, int* __restrict__ eids, float2* __restrict__ gw)
{
    int id = blockIdx.x;
    if (id < 21120) {
        // ---- weight transpose: 32x32 fp32 tile -> bf16 fragment-swizzled block ----
        const float* src; bf16* dst; int C, rt, ct, nkt;
        if (id < 5632)       { int t = id;         int e = t / 704, m = t % 704; C = 704;
                               src = W1 + (size_t)e * 1024 * 704;  dst = w1t + (size_t)e * 720896;
                               ct = m % 22; rt = m / 22; nkt = 32; }
        else if (id < 11264) { int t = id - 5632;  int e = t / 704, m = t % 704; C = 704;
                               src = W3 + (size_t)e * 1024 * 704;  dst = w3t + (size_t)e * 720896;
                               ct = m % 22; rt = m / 22; nkt = 32; }
        else if (id < 16896) { int t = id - 11264; int e = t / 704, m = t % 704; C = 1024;
                               src = W2 + (size_t)e * 704 * 1024;  dst = w2t + (size_t)e * 720896;
                               ct = m % 32; rt = m / 32; nkt = 22; }
        else if (id < 18304) { int t = id - 16896; C = 1408; src = Ws1;
                               ct = t % 44; rt = t / 44; nkt = 32;
                               int ep = (ct >= 22) ? 1 : 0; ct -= 22 * ep;
                               src += (size_t)704 * ep;
                               dst = ws1t + (size_t)ep * 720896; }
        else if (id < 19712) { int t = id - 18304; C = 1408; src = Ws3;
                               ct = t % 44; rt = t / 44; nkt = 32;
                               int ep = (ct >= 22) ? 1 : 0; ct -= 22 * ep;
                               src += (size_t)704 * ep;
                               dst = ws3t + (size_t)ep * 720896; }
        else                 { int t = id - 19712; C = 1024; src = Ws2;
                               ct = t % 32; rt = t / 32; nkt = 22;
                               int ep = (rt >= 22) ? 1 : 0; rt -= 22 * ep;
                               src += (size_t)704 * 1024 * ep;
                               dst = ws2t + (size_t)ep * 720896; }

        __shared__ float tl[32][33];
        int c0 = ct * 32, r0 = rt * 32;      // r = k dim, c = n dim (src [K][N] row-major)
        int row  = threadIdx.x >> 3;
        int col4 = (threadIdx.x & 7) * 4;
        float4 v = *(const float4*)&src[(size_t)(r0 + row) * C + c0 + col4];
        tl[row][col4 + 0] = v.x; tl[row][col4 + 1] = v.y;
        tl[row][col4 + 2] = v.z; tl[row][col4 + 3] = v.w;
        __syncthreads();
        // coalesced store: thread t writes elements (t&127)*4..+3 of one 512-elem
        // block; wave = 512B contiguous (r7 post-mortem: old scatter was ~50%
        // cacheline density). Same element mapping as before, re-grouped.
        int t2   = threadIdx.x;
        int half = t2 >> 7;                  // n-group within the 32-col tile
        int ei   = (t2 & 127) * 4;           // element index in 512-block
        int cc   = ei >> 7;
        int nr   = (ei >> 3) & 15;
        int jj   = ei & 7;                   // 0 or 4
        int n_loc = half * 16 + nr;
        int k_loc = cc * 8 + jj;
        bf16x4 o;
        o[0] = (bf16)tl[k_loc + 0][n_loc];
        o[1] = (bf16)tl[k_loc + 1][n_loc];
        o[2] = (bf16)tl[k_loc + 2][n_loc];
        o[3] = (bf16)tl[k_loc + 3][n_loc];
        int ng = ct * 2 + half;
        *(bf16x4*)&dst[(size_t)(((ng * nkt + rt) << 9) + ei)] = o;
        return;
    }
    id -= 21120;
    if (id < 4096) {
        // ---- x -> bf16 ----
        int i = id * 256 + threadIdx.x;      // < 1048576 = NTOK*DM/4 exactly
        float4 v = ((const float4*)x)[i];
        bf16x4 o;
        o[0] = (bf16)v.x; o[1] = (bf16)v.y; o[2] = (bf16)v.z; o[3] = (bf16)v.w;
        ((bf16x4*)xb)[i] = o;
        return;
    }
    id -= 4096;
    {
        // ---- router: fp32 logits, softmax, top-2 per token ----
        int n    = id * 4 + (threadIdx.x >> 6);
        int lane = threadIdx.x & 63;
        const float* xrow = x + (size_t)n * DM;
        float xr[16];
        #pragma unroll
        for (int j = 0; j < 16; j++) xr[j] = xrow[lane + 64 * j];
        float logit[NE];
        #pragma unroll
        for (int e = 0; e < NE; e++) {
            const float* wr = Wg + e * DM;
            float s = 0.f;
            #pragma unroll
            for (int j = 0; j < 16; j++) s += xr[j] * wr[lane + 64 * j];
            #pragma unroll
            for (int off = 32; off; off >>= 1) s += __shfl_xor(s, off, 64);
            logit[e] = s;
        }
        if (lane == 0) {
            int i0 = 0;
            #pragma unroll
            for (int e = 1; e < NE; e++) if (logit[e] > logit[i0]) i0 = e;
            int i1 = (i0 == 0) ? 1 : 0;
            #pragma unroll
            for (int e = 0; e < NE; e++) if (e != i0 && logit[e] > logit[i1]) i1 = e;
            float m = logit[0];
            #pragma unroll
            for (int e = 1; e < NE; e++) m = fmaxf(m, logit[e]);
            float denom = 0.f;
            #pragma unroll
            for (int e = 0; e < NE; e++) denom += expf(logit[e] - m);
            float g0 = expf(logit[i0] - m) / denom;
            float g1 = expf(logit[i1] - m) / denom;
            float inv = 1.f / (g0 + g1 + 1e-20f);
            eids[n] = i0 | (i1 << 16);
            gw[n] = make_float2(g0 * inv, g1 * inv);
        }
    }
}

// ---------------- router pass 2: list build + per-token slot record ----------------
__global__ __launch_bounds__(128) void build_lists(
    const int* __restrict__ eids, const float2* __restrict__ gw,
    int* __restrict__ cnt, int* __restrict__ tok, float* __restrict__ wgt,
    int2* __restrict__ slots)
{
    __shared__ int lcnt[NE];
    __shared__ int gbase[NE];
    int t = threadIdx.x;
    int n = blockIdx.x * 128 + t;
    if (t < NE) lcnt[t] = 0;
    __syncthreads();
    int packed = eids[n];
    float2 w = gw[n];
    int e0 = packed & 0xffff, e1 = packed >> 16;
    int s0 = atomicAdd(&lcnt[e0], 1);
    int s1 = atomicAdd(&lcnt[e1], 1);
    __syncthreads();
    if (t < NE) gbase[t] = atomicAdd(&cnt[t], lcnt[t]);
    __syncthreads();
    int p0 = gbase[e0] + s0, p1 = gbase[e1] + s1;
    tok[e0 * NTOK + p0] = n; wgt[e0 * NTOK + p0] = w.x;
    tok[e1 * NTOK + p1] = n; wgt[e1 * NTOK + p1] = w.y;
    slots[n] = make_int2((e0 << 16) | p0, (e1 << 16) | p1);
}

// ---------------- prefix + XCD-pinned work lists (decide serial, expand parallel) ----
// entry: (e<<20) | (mtile<<8) | xtile ; -1 = no-op slot.
__global__ void prefix_kernel(const int* __restrict__ cnt, int* __restrict__ pfx,
                              int* __restrict__ map1, int* __restrict__ map2)
{
    __shared__ int sx1[144], ss1[144], se1[144];   // gemm1 segments (<=136)
    __shared__ int sx2[112], ss2[112], se2[112];   // gemm2 segments (<=104)
    __shared__ int ns1s, ns2s;
    int t = threadIdx.x;
    for (int i = t; i < 8 * MAP1_CAP; i += 64) map1[i] = -1;
    for (int i = t; i < 8 * MAP2_CAP; i += 64) map2[i] = -1;

    if (t == 0) {
        int s = 0;
        for (int e = 0; e < NEX; e++) { pfx[e] = s; s += (e < NE) ? cnt[e] : NTOK; }
        pfx[NEX] = s;

        int ntl[NEX];
        int tot1 = 0;
        for (int e = 0; e < NEX; e++) {
            int c = (e < NE) ? cnt[e] : NTOK;
            ntl[e] = (c + 127) >> 7;
            tot1 += ntl[e];
        }
        // ---- gemm1 decisions: units of 11 h-blocks; uniform work; slot-balance ----
        {
            int len[8] = {0,0,0,0,0,0,0,0};
            int avg = (tot1 * 11 + 7) >> 3;
            int ns = 0, k = 0;
            for (int e = 0; e < NEX; e++) {
                k = 0;
                for (int q = 1; q < 8; q++) if (len[q] < len[k]) k = q;
                for (int tt = 0; tt < ntl[e]; tt++) {
                    if (len[k] >= avg) {
                        k = 0;
                        for (int q = 1; q < 8; q++) if (len[q] < len[k]) k = q;
                    }
                    if (len[k] + 11 > MAP1_CAP) {
                        k = 0;
                        for (int q = 1; q < 8; q++) if (len[q] < len[k]) k = q;
                    }
                    sx1[ns] = k; ss1[ns] = len[k]; se1[ns] = (e << 20) | (tt << 8);
                    len[k] += 11; ns++;
                }
            }
            ns1s = ns;
        }
        // ---- gemm2 decisions: units of 8 d-blocks; WORK-weighted (22 vs 44) ----
        {
            int wrk[8] = {0,0,0,0,0,0,0,0};
            int slt[8] = {0,0,0,0,0,0,0,0};
            int totw = 0;
            for (int e = 0; e <= NE; e++)
                totw += (e < NE) ? ntl[e] * 8 * 22 : (NTOK >> 7) * 8 * 44;
            int avg = (totw + 7) >> 3;
            int ns = 0, k = 0;
            for (int e = 0; e <= NE; e++) {
                int nt2 = (e < NE) ? ntl[e] : (NTOK >> 7);
                int wpd = (e < NE) ? 22 : 44;
                k = 0;
                for (int q = 1; q < 8; q++) if (wrk[q] < wrk[k]) k = q;
                for (int tt = 0; tt < nt2; tt++) {
                    if (wrk[k] >= avg) {
                        k = 0;
                        for (int q = 1; q < 8; q++) if (wrk[q] < wrk[k]) k = q;
                    }
                    if (slt[k] + 8 > MAP2_CAP) {
                        k = 0;
                        for (int q = 1; q < 8; q++) if (slt[q] < slt[k]) k = q;
                    }
                    sx2[ns] = k; ss2[ns] = slt[k]; se2[ns] = (e << 20) | (tt << 8);
                    slt[k] += 8; wrk[k] += 8 * wpd; ns++;
                }
            }
            ns2s = ns;
        }
    }
    __syncthreads();
    int n1 = ns1s, n2 = ns2s;
    for (int i = t; i < n1 * 11; i += 64) {
        int sg = i / 11, h = i - sg * 11;
        map1[(ss1[sg] + h) * 8 + sx1[sg]] = se1[sg] | h;
    }
    for (int i = t; i < n2 * 8; i += 64) {
        int sg = i >> 3, d = i & 7;
        map2[(ss2[sg] + d) * 8 + sx2[sg]] = se2[sg] | d;
    }
}

// ---------------- GEMM1: act = silu(A@W1) * (A@W3) ---------------------------------
// Triple-buffered, single raw barrier per K-step, counted vmcnt (never 0 in steady
// state): loads issued at step t complete during steps t..t+1, hidden under MFMA.
__global__ __launch_bounds__(256) void gemm1_swiglu(
    const bf16* __restrict__ xb,
    const bf16* __restrict__ w1t, const bf16* __restrict__ w3t,
    const bf16* __restrict__ ws1t, const bf16* __restrict__ ws3t,
    bf16* __restrict__ act,
    const int* __restrict__ cnt, const int* __restrict__ pfx,
    const int* __restrict__ tok, const int* __restrict__ map)
{
    int b = blockIdx.x;
    int ent = map[(b >> 3) * 8 + (b & 7)];
    if (ent < 0) return;
    int e  = ent >> 20;
    int m0 = ((ent >> 8) & 0xfff) << 7;
    int h0 = (ent & 255) * 64;
    int count = (e < NE) ? cnt[e] : NTOK;
    int base = pfx[e];
    const bf16 *B1, *B3;
    if (e < NE) { B1 = w1t + (size_t)e * 720896;         B3 = w3t + (size_t)e * 720896; }
    else        { B1 = ws1t + (size_t)(e - NE) * 720896; B3 = ws3t + (size_t)(e - NE) * 720896; }
    const int* tlist = (e < NE) ? tok + e * NTOK : nullptr;

    __shared__ bf16 As[3][8 * 512];     // 24 KB
    __shared__ bf16 B1s[3][4 * 512];    // 12 KB
    __shared__ bf16 B3s[3][4 * 512];    // 12 KB  -> 48 KB total, 3 blocks/CU

    int tid = threadIdx.x, w = tid >> 6, lane = tid & 63;

    int r3 = lane >> 2;
    int cx = (lane & 3) ^ ((r3 >> 1) & 3);
    int sA0 = m0 + 32 * w + r3, sA1 = sA0 + 16;
    int rA0 = tlist ? (sA0 < count ? tlist[sA0] : 0) : (sA0 < count ? sA0 : 0);
    int rA1 = tlist ? (sA1 < count ? tlist[sA1] : 0) : (sA1 < count ? sA1 : 0);
    const bf16* ga0 = xb + (size_t)rA0 * DM + cx * 8;
    const bf16* ga1 = xb + (size_t)rA1 * DM + cx * 8;
    const bf16* gb1 = B1 + ((size_t)((h0 >> 4) + w) * 32) * 512 + lane * 8;
    const bf16* gb3 = B3 + ((size_t)((h0 >> 4) + w) * 32) * 512 + lane * 8;
    bf16* aA0 = &As[0][0]  + (2 * w) * 512;
    bf16* aA1 = aA0 + 512;
    bf16* aB1 = &B1s[0][0] + w * 512;
    bf16* aB3 = &B3s[0][0] + w * 512;

    int rl = lane & 15, ch = lane >> 4;
    int uA = 4 * rl + (ch ^ ((rl >> 1) & 3));
    int gA = (w & 1) * 4;
    int gB = (w >> 1) * 2;
    int wm = (w & 1) * 64, wn = (w >> 1) * 32;

    f32x4 acch[4][2], accg[4][2];
    #pragma unroll
    for (int i = 0; i < 4; i++)
        #pragma unroll
        for (int j = 0; j < 2; j++) {
            acch[i][j] = (f32x4){0.f, 0.f, 0.f, 0.f};
            accg[i][j] = (f32x4){0.f, 0.f, 0.f, 0.f};
        }

#define STAGE1(bs) do { \
        async_cp16(ga0, aA0 + (bs) * 4096); \
        async_cp16(ga1, aA1 + (bs) * 4096); \
        async_cp16(gb1, aB1 + (bs) * 2048); \
        async_cp16(gb3, aB3 + (bs) * 2048); \
        ga0 += 32; ga1 += 32; gb1 += 512; gb3 += 512; \
    } while (0)

    STAGE1(0);                                           // tile 0 (4 loads in flight)
    STAGE1(1);                                           // tile 1 (8 in flight)
    asm volatile("s_waitcnt vmcnt(4)" ::: "memory");     // tile 0 complete
    __builtin_amdgcn_s_barrier();

    int rb = 0, sb = 2;
    for (int k0 = 0; k0 < 32; k0++) {
        const bf16* Ab  = &As[0][0]  + rb * 4096;
        const bf16* B1b = &B1s[0][0] + rb * 2048;
        const bf16* B3b = &B3s[0][0] + rb * 2048;
        bf16x8 af[4], b1f[2], b3f[2];
        #pragma unroll
        for (int i = 0; i < 4; i++) af[i] = *(const bf16x8*)(Ab + (gA + i) * 512 + uA * 8);
        #pragma unroll
        for (int j = 0; j < 2; j++) {
            b1f[j] = *(const bf16x8*)(B1b + (gB + j) * 512 + lane * 8);
            b3f[j] = *(const bf16x8*)(B3b + (gB + j) * 512 + lane * 8);
        }
        if (k0 < 30) STAGE1(sb);                         // stage tile k0+2
        #pragma unroll
        for (int i = 0; i < 4; i++)
            #pragma unroll
            for (int j = 0; j < 2; j++) {
                acch[i][j] = __builtin_amdgcn_mfma_f32_16x16x32_bf16(af[i], b1f[j], acch[i][j], 0, 0, 0);
                accg[i][j] = __builtin_amdgcn_mfma_f32_16x16x32_bf16(af[i], b3f[j], accg[i][j], 0, 0, 0);
            }
        if (k0 < 30)       asm volatile("s_waitcnt vmcnt(4)" ::: "memory"); // tile k0+1 ready
        else if (k0 == 30) asm volatile("s_waitcnt vmcnt(0)" ::: "memory"); // last tile ready
        __builtin_amdgcn_sched_barrier(0);
        __builtin_amdgcn_s_barrier();
        rb = (rb == 2) ? 0 : rb + 1;
        sb = (sb == 2) ? 0 : sb + 1;
    }
#undef STAGE1

    #pragma unroll
    for (int i = 0; i < 4; i++)
        #pragma unroll
        for (int j = 0; j < 2; j++)
            #pragma unroll
            for (int r = 0; r < 4; r++) {
                int row = wm + i * 16 + ch * 4 + r;
                int s2 = m0 + row;
                if (s2 < count) {
                    float hv = acch[i][j][r], gv = accg[i][j][r];
                    float a = hv / (1.f + expf(-hv)) * gv;
                    act[(size_t)(base + s2) * HE + h0 + wn + j * 16 + rl] = (bf16)a;
                }
            }
}

// ---------------- GEMM2 unified (routed + shared), triple-buffered counted-vmcnt ------
// e<8 : yr[slot] = bf16(gate * act@W2)   (22 K-steps)
// e==8: out[n]   = act_sh @ Ws2, K=1408 via two 22-step segments, fp32 plain stores
__global__ __launch_bounds__(256) void gemm2_all(
    const bf16* __restrict__ act,
    const bf16* __restrict__ w2t, const bf16* __restrict__ ws2t,
    bf16* __restrict__ yr, float* __restrict__ out,
    const int* __restrict__ cnt, const int* __restrict__ pfx,
    const float* __restrict__ wgt, const int* __restrict__ map)
{
    int b = blockIdx.x;
    int ent = map[(b >> 3) * 8 + (b & 7)];
    if (ent < 0) return;
    int e  = ent >> 20;
    int m0 = ((ent >> 8) & 0xfff) << 7;
    int d0 = (ent & 255) * 128;

    __shared__ bf16 As[3][8 * 512];     // 24 KB
    __shared__ bf16 Bs[3][8 * 512];     // 24 KB -> 48 KB total

    int tid = threadIdx.x, w = tid >> 6, lane = tid & 63;

    int r3 = lane >> 2;
    int cx = (lane & 3) ^ ((r3 >> 1) & 3);
    int sA0 = m0 + 32 * w + r3, sA1 = sA0 + 16;
    int rl = lane & 15, ch = lane >> 4;
    int uA = 4 * rl + (ch ^ ((rl >> 1) & 3));
    int gA = (w & 1) * 4, gB = (w >> 1) * 4;
    int wm = (w & 1) * 64, wn = (w >> 1) * 64;

    bf16* aA0 = &As[0][0] + (2 * w) * 512;
    bf16* aA1 = aA0 + 512;
    bf16* aB0 = &Bs[0][0] + (2 * w) * 512;
    bf16* aB1 = aB0 + 512;

    int count, base; const bf16* Bp;
    if (e < NE) { count = cnt[e]; base = pfx[e]; Bp = w2t + (size_t)e * 720896; }
    else        { count = NTOK;   base = NTOK * 2; Bp = ws2t; }   // pfx[8]==8192 always

    int a0 = (sA0 < count) ? (base + sA0) : base;
    int a1 = (sA1 < count) ? (base + sA1) : base;
    const bf16* ga0 = act + (size_t)a0 * HE + cx * 8;
    const bf16* ga1 = act + (size_t)a1 * HE + cx * 8;
    const bf16* gb0 = Bp + ((size_t)((d0 >> 4) + 2 * w) * 22) * 512 + lane * 8;
    const bf16* gb1 = Bp + ((size_t)((d0 >> 4) + 2 * w + 1) * 22) * 512 + lane * 8;

    f32x4 acc[4][4];
    #pragma unroll
    for (int i = 0; i < 4; i++)
        #pragma unroll
        for (int j = 0; j < 4; j++) acc[i][j] = (f32x4){0.f, 0.f, 0.f, 0.f};

#define STAGE2(bs) do { \
        async_cp16(ga0, aA0 + (bs) * 4096); \
        async_cp16(ga1, aA1 + (bs) * 4096); \
        async_cp16(gb0, aB0 + (bs) * 4096); \
        async_cp16(gb1, aB1 + (bs) * 4096); \
        ga0 += 32; ga1 += 32; gb0 += 512; gb1 += 512; \
    } while (0)

    int total = (e < NE) ? 22 : 44;
    STAGE2(0);
    STAGE2(1);
    asm volatile("s_waitcnt vmcnt(4)" ::: "memory");
    __builtin_amdgcn_s_barrier();

    int rb = 0, sb = 2;
    for (int kt = 0; kt < total; kt++) {
        const bf16* Ab = &As[0][0] + rb * 4096;
        const bf16* Bb = &Bs[0][0] + rb * 4096;
        bf16x8 af[4], bf_[4];
        #pragma unroll
        for (int i = 0; i < 4; i++) af[i]  = *(const bf16x8*)(Ab + (gA + i) * 512 + uA * 8);
        #pragma unroll
        for (int j = 0; j < 4; j++) bf_[j] = *(const bf16x8*)(Bb + (gB + j) * 512 + lane * 8);
        int nx = kt + 2;
        if (nx < total) {
            if (nx == 22) {                 // only when total==44: switch to shared half 1
                ga0 = act + (size_t)(12288 + sA0) * HE + cx * 8;   // pfx[9]==12288 always
                ga1 = act + (size_t)(12288 + sA1) * HE + cx * 8;
                const bf16* B2 = ws2t + 720896;
                gb0 = B2 + ((size_t)((d0 >> 4) + 2 * w) * 22) * 512 + lane * 8;
                gb1 = B2 + ((size_t)((d0 >> 4) + 2 * w + 1) * 22) * 512 + lane * 8;
            }
            STAGE2(sb);
        }
        #pragma unroll
        for (int i = 0; i < 4; i++)
            #pragma unroll
            for (int j = 0; j < 4; j++)
                acc[i][j] = __builtin_amdgcn_mfma_f32_16x16x32_bf16(af[i], bf_[j], acc[i][j], 0, 0, 0);
        if (nx < total)       asm volatile("s_waitcnt vmcnt(4)" ::: "memory");
        else if (nx == total) asm volatile("s_waitcnt vmcnt(0)" ::: "memory");
        __builtin_amdgcn_sched_barrier(0);
        __builtin_amdgcn_s_barrier();
        rb = (rb == 2) ? 0 : rb + 1;
        sb = (sb == 2) ? 0 : sb + 1;
    }
#undef STAGE2

    if (e < NE) {
        const float* wl = wgt + e * NTOK;
        #pragma unroll
        for (int i = 0; i < 4; i++) {
            #pragma unroll
            for (int r = 0; r < 4; r++) {
                int row = wm + i * 16 + ch * 4 + r;
                int s2 = m0 + row;
                if (s2 < count) {
                    float wt = wl[s2];
                    bf16* yrow = yr + (size_t)(base + s2) * DM + d0 + wn;
                    #pragma unroll
                    for (int j = 0; j < 4; j++)
                        yrow[j * 16 + rl] = (bf16)(wt * acc[i][j][r]);
                }
            }
        }
    } else {
        #pragma unroll
        for (int i = 0; i < 4; i++) {
            #pragma unroll
            for (int r = 0; r < 4; r++) {
                int row = wm + i * 16 + ch * 4 + r;
                float* orow = out + (size_t)(m0 + row) * DM + d0 + wn;
                #pragma unroll
                for (int j = 0; j < 4; j++)
                    orow[j * 16 + rl] = acc[i][j][r];
            }
        }
    }
}

// ---------------- fuse: out[n] += yr[slot0] + yr[slot1] ----------------
__global__ __launch_bounds__(256) void fuse_add(
    const bf16* __restrict__ yr, const int2* __restrict__ slots,
    const int* __restrict__ pfx, float* __restrict__ out)
{
    int n = blockIdx.x;
    int2 s = slots[n];
    int slot0 = pfx[s.x >> 16] + (s.x & 0xffff);
    int slot1 = pfx[s.y >> 16] + (s.y & 0xffff);
    const bf16* y0 = yr + (size_t)slot0 * DM;
    const bf16* y1 = yr + (size_t)slot1 * DM;
    float* orow = out + (size_t)n * DM;
    int d = threadIdx.x * 4;
    bf16x4 a = *(const bf16x4*)(y0 + d);
    bf16x4 b = *(const bf16x4*)(y1 + d);
    float4 o = *(float4*)(orow + d);
    o.x += (float)a[0] + (float)b[0];
    o.y += (float)a[1] + (float)b[1];
    o.z += (float)a[2] + (float)b[2];
    o.w += (float)a[3] + (float)b[3];
    *(float4*)(orow + d) = o;
}

extern "C" void kernel_launch(void* const* d_in, const int* in_sizes, int n_in,
                              void* d_out, int out_size, void* d_ws, size_t ws_size,
                              hipStream_t stream)
{
    const float* x   = (const float*)d_in[0];
    const float* Wg  = (const float*)d_in[1];
    const float* W1  = (const float*)d_in[2];
    const float* W3  = (const float*)d_in[3];
    const float* W2  = (const float*)d_in[4];
    const float* Ws1 = (const float*)d_in[5];
    const float* Ws3 = (const float*)d_in[6];
    const float* Ws2 = (const float*)d_in[7];
    float* out = (float*)d_out;
    char*  ws  = (char*)d_ws;

    int*    cnt   = (int*)(ws + OFF_CNT);
    int*    pfx   = (int*)(ws + OFF_CNT + 32);
    int*    tok   = (int*)(ws + OFF_TOK);
    float*  wgt   = (float*)(ws + OFF_WGT);
    bf16*   xb    = (bf16*)(ws + OFF_XB);
    bf16*   w1t   = (bf16*)(ws + OFF_W1T);
    bf16*   w3t   = (bf16*)(ws + OFF_W3T);
    bf16*   w2t   = (bf16*)(ws + OFF_W2T);
    bf16*   ws1t  = (bf16*)(ws + OFF_WS1T);
    bf16*   ws3t  = (bf16*)(ws + OFF_WS3T);
    bf16*   ws2t  = (bf16*)(ws + OFF_WS2T);
    bf16*   act   = (bf16*)(ws + OFF_ACT);
    int*    eids  = (int*)(ws + OFF_EIDS);
    int*    map1  = (int*)(ws + OFF_MAP1);   // aliases eids (dead after build_lists)
    int*    map2  = (int*)(ws + OFF_MAP2);
    float2* gw    = (float2*)(ws + OFF_GW);
    int2*   slots = (int2*)(ws + OFF_SLOT);
    bf16*   yr    = (bf16*)(ws + OFF_YR);    // aliases w1t/w3t (dead after gemm1)

    hipMemsetAsync(ws, 0, 256, stream);

    // fused prep: transpose (coalesced stores) + cvt_x + router, one launch
    prep_all<<<21120 + 4096 + 1024, 256, 0, stream>>>(
        x, Wg, W1, W3, W2, Ws1, Ws3, Ws2,
        w1t, w3t, w2t, ws1t, ws3t, ws2t, xb, eids, gw);

    build_lists<<<32, 128, 0, stream>>>(eids, gw, cnt, tok, wgt, slots);
    prefix_kernel<<<1, 64, 0, stream>>>(cnt, pfx, map1, map2);

    // XCD-pinned 1D grids (blockIdx%8 -> XCD; map holds per-XCD lists)
    gemm1_swiglu<<<8 * MAP1_CAP, 256, 0, stream>>>(
        xb, w1t, w3t, ws1t, ws3t, act, cnt, pfx, tok, map1);

    gemm2_all<<<8 * MAP2_CAP, 256, 0, stream>>>(
        act, w2t, ws2t, yr, out, cnt, pfx, wgt, map2);

    fuse_add<<<NTOK, 256, 0, stream>>>(yr, slots, pfx, out);
}